// Round 13
// baseline (316.809 us; speedup 1.0000x reference)
//
#include <hip/hip_runtime.h>
#include <hip/hip_bf16.h>

// XCAttention: B=8, N=4096, C=768, H=32, D=24
// K0a: x fp32->bf16; K0b: both W transposed->bf16 (single launch);
// K1: qkv GEMM 128x128, BK=32, 256 thr, 3-slot, 3 blocks/CU (best ratio-to-ceiling);
// KA: partial Grams; KB: softmax; KC: attn@v -> y;
// K3: proj GEMM same structure, fp32 nt out.

#define DEVI __device__ __forceinline__

typedef __attribute__((ext_vector_type(8))) short bf16x8;
typedef __attribute__((ext_vector_type(4))) float f32x4;
typedef unsigned int u32;
typedef unsigned short u16;

DEVI u16 f2bf(float f) {  // RNE float->bf16
  union { float f; u32 u; } x; x.f = f;
  u32 r = x.u + 0x7FFFu + ((x.u >> 16) & 1u);
  return (u16)(r >> 16);
}

DEVI void gload_lds16(const void* g, void* l) {
  __builtin_amdgcn_global_load_lds((__attribute__((address_space(1))) void*)g,
                                   (__attribute__((address_space(3))) void*)l, 16, 0, 0);
}

// ---------------- K0a: fp32 -> bf16 convert ----------------
__global__ __launch_bounds__(256) void cvt_kernel(const float* __restrict__ in,
                                                  u16* __restrict__ out, int n8) {
  int i = blockIdx.x * 256 + threadIdx.x;
  if (i >= n8) return;
  long o = (long)i * 8;
  float4 a = *(const float4*)(in + o);
  float4 b = *(const float4*)(in + o + 4);
  uint4 v;
  v.x = f2bf(a.x) | ((u32)f2bf(a.y) << 16);
  v.y = f2bf(a.z) | ((u32)f2bf(a.w) << 16);
  v.z = f2bf(b.x) | ((u32)f2bf(b.y) << 16);
  v.w = f2bf(b.z) | ((u32)f2bf(b.w) << 16);
  *(uint4*)(out + o) = v;
}

// ---------------- K0b: both weights, W (K x N fp32) -> Wt (N x K bf16) ----------------
__global__ __launch_bounds__(256) void transpose_cvt2(const float* __restrict__ Wq,
                                                      u16* __restrict__ Wqt,
                                                      const float* __restrict__ Wp,
                                                      u16* __restrict__ Wpt) {
  __shared__ float tile[32][33];
  int bx = blockIdx.x;
  const float* W; u16* Wt; int N, n0;
  if (bx < 72) { W = Wq; Wt = Wqt; N = 2304; n0 = bx * 32; }
  else         { W = Wp; Wt = Wpt; N = 768;  n0 = (bx - 72) * 32; }
  int k0 = blockIdx.y * 32;
  int tx = threadIdx.x, ty = threadIdx.y;  // (32,8)
  #pragma unroll
  for (int i = 0; i < 4; ++i)
    tile[ty + 8 * i][tx] = W[(long)(k0 + ty + 8 * i) * N + n0 + tx];
  __syncthreads();
  #pragma unroll
  for (int i = 0; i < 4; ++i)
    Wt[(long)(n0 + ty + 8 * i) * 768 + k0 + tx] = f2bf(tile[tx][ty + 8 * i]);
}

// ---------------- 128x128 bf16 GEMM, 256 thr, 3 blocks/CU ----------------
// A: M x K bf16 row-major. Bt: N x K bf16 row-major. C = A@Bt^T + bias.
// 4 waves (2Mx2N), 64x64 wave tiles, BK=32, 3-slot rotation. LDS 48KB:
// A 3x8KB @0, B 3x8KB @24576 -> 3 blocks/CU (147KB), 12 waves/CU.
// Proven st_16x32 swizzle byte^=((byte>>9)&1)<<5 (pre-swizzled gload source,
// swizzled ds_read addr). Per tile: stage(kt+2) 4 gloads; vmcnt(8); barrier;
// 8 ds_read_b128 + 16 MFMA (setprio); barrier.
#define STAGE3(ktile, slot)                                                    \
  { _Pragma("unroll") for (int j_ = 0; j_ < 2; ++j_) {                         \
      gload_lds16(Ag + soffA[j_] + (ktile) * 32,                               \
                  lds + (slot) * 8192 + j_ * 4096 + sdst);                     \
      gload_lds16(Bg + soffB[j_] + (ktile) * 32,                               \
                  lds + 24576 + (slot) * 8192 + j_ * 4096 + sdst); } }

template<int NT, int BF16_OUT>
__global__ __launch_bounds__(256, 3) void gemm3c_kernel(
    const u16* __restrict__ A, const u16* __restrict__ Bt,
    const float* __restrict__ bias, void* __restrict__ Cout,
    int M, int N) {
  constexpr int K = NT * 32;
  __shared__ __attribute__((aligned(128))) char lds[49152];

  int nbx = N >> 7;
  int nwg = gridDim.x;
  int bid = blockIdx.x;
  bid = (bid & 7) * (nwg >> 3) + (bid >> 3);  // bijective XCD swizzle (nwg%8==0)
  int bx = bid % nbx, by = bid / nbx;

  int t = threadIdx.x;
  int w = t >> 6, l = t & 63;
  int wr = w >> 1, wc = w & 1;
  int l16 = l & 15, l4 = l >> 4;

  int cbb = (l4 * 16) ^ ((l16 & 8) << 2);
  int pA0 = (wr * 64 + l16) * 64 + cbb;          // + slot*8192 + mi*1024
  int pB0 = (wc * 64 + l16) * 64 + cbb;          // + 24576 + slot*8192 + n*1024

  int soffA[2], soffB[2];
  #pragma unroll
  for (int j = 0; j < 2; ++j) {
    int p = (j * 256 + t) * 16;
    int lb = p ^ (((p >> 9) & 1) << 5);
    soffA[j] = (lb >> 6) * K + ((lb & 63) >> 1);
    soffB[j] = soffA[j];
  }

  const u16* Ag = A + (long)by * 128 * K;
  const u16* Bg = Bt + (long)bx * 128 * K;
  int sdst = w * 1024;

  f32x4 acc[4][4] = {};

  STAGE3(0, 0);
  STAGE3(1, 1);

  #pragma unroll
  for (int kt = 0; kt < NT; ++kt) {
    int rs = kt % 3;
    if (kt + 2 < NT) {
      STAGE3(kt + 2, (kt + 2) % 3);
      asm volatile("s_waitcnt vmcnt(8)" ::: "memory");
    } else if (kt + 2 == NT) {
      asm volatile("s_waitcnt vmcnt(4)" ::: "memory");
    } else {
      asm volatile("s_waitcnt vmcnt(0)" ::: "memory");
    }
    __builtin_amdgcn_sched_barrier(0);
    __builtin_amdgcn_s_barrier();
    __builtin_amdgcn_sched_barrier(0);

    bf16x8 aF[4], bF[4];
    #pragma unroll
    for (int mi = 0; mi < 4; ++mi)
      aF[mi] = *(const bf16x8*)(lds + rs * 8192 + mi * 1024 + pA0);
    #pragma unroll
    for (int n = 0; n < 4; ++n)
      bF[n] = *(const bf16x8*)(lds + 24576 + rs * 8192 + n * 1024 + pB0);

    __builtin_amdgcn_s_setprio(1);
    #pragma unroll
    for (int mi = 0; mi < 4; ++mi)
      #pragma unroll
      for (int n = 0; n < 4; ++n)
        acc[mi][n] = __builtin_amdgcn_mfma_f32_16x16x32_bf16(aF[mi], bF[n], acc[mi][n], 0, 0, 0);
    __builtin_amdgcn_s_setprio(0);
    __builtin_amdgcn_s_barrier();
    __builtin_amdgcn_sched_barrier(0);
  }

  #pragma unroll
  for (int mi = 0; mi < 4; ++mi) {
    int row0 = by * 128 + wr * 64 + mi * 16 + l4 * 4;
    #pragma unroll
    for (int n = 0; n < 4; ++n) {
      int col = bx * 128 + wc * 64 + n * 16 + l16;
      float bv = bias[col];
      #pragma unroll
      for (int j = 0; j < 4; ++j) {
        long idx = (long)(row0 + j) * N + col;
        float v = acc[mi][n][j] + bv;
        if (BF16_OUT) ((u16*)Cout)[idx] = f2bf(v);
        else          __builtin_nontemporal_store(v, (float*)Cout + idx);
      }
    }
  }
}

// ---------------- KA: partial Grams ----------------
#define PFQK(nc, rq, rk)                                                       \
  { long cb = (long)(nc) * 589824;                                             \
    _Pragma("unroll") for (int i = 0; i < 3; ++i) {                            \
      rq[i] = *(const uint4*)(qbase + cb + offI[i]);                           \
      rk[i] = *(const uint4*)(kbase + cb + offI[i]); } }

#define WRQK(rq, rk)                                                           \
  { _Pragma("unroll") for (int i = 0; i < 3; ++i) {                            \
      const u32* pq = (const u32*)&rq[i];                                      \
      const u32* pk = (const u32*)&rk[i];                                      \
      _Pragma("unroll") for (int j = 0; j < 4; ++j) {                          \
        int d = sI[i] * 8 + 2 * j;                                             \
        qt[d][nI[i]] = (u16)pq[j]; qt[d + 1][nI[i]] = (u16)(pq[j] >> 16);      \
        kt[d][nI[i]] = (u16)pk[j]; kt[d + 1][nI[i]] = (u16)(pk[j] >> 16); } } }

#define GRAM8                                                                  \
  { _Pragma("unroll") for (int ks = 0; ks < 8; ++ks) {                         \
      int koff = ks * 32 + l4 * 8;                                             \
      bf16x8 qa = *(const bf16x8*)&qt[fm * 16 + l16][koff];                    \
      bf16x8 qb = *(const bf16x8*)&qt[fn * 16 + l16][koff];                    \
      bf16x8 ka = *(const bf16x8*)&kt[fm * 16 + l16][koff];                    \
      bf16x8 kb = *(const bf16x8*)&kt[fn * 16 + l16][koff];                    \
      accG = __builtin_amdgcn_mfma_f32_16x16x32_bf16(qa, kb, accG, 0, 0, 0);   \
      accQ = __builtin_amdgcn_mfma_f32_16x16x32_bf16(qa, qb, accQ, 0, 0, 0);   \
      accK = __builtin_amdgcn_mfma_f32_16x16x32_bf16(ka, kb, accK, 0, 0, 0); } }

__global__ __launch_bounds__(256) void gram_kernel(const u16* __restrict__ qkv,
                                                   float* __restrict__ gram) {
  __shared__ u16 qt[32][280];
  __shared__ u16 kt[32][280];

  int bid = blockIdx.x;
  int bh = bid >> 2, s = bid & 3;
  int b = bh >> 5, h = bh & 31;
  int t = threadIdx.x;
  int w = t >> 6, l = t & 63;
  int l16 = l & 15, l4 = l >> 4;
  int fm = w >> 1, fn = w & 1;

  for (int i = t; i < 32 * 280; i += 256) { qt[0][i] = 0; kt[0][i] = 0; }

  int nI[3], sI[3], offI[3];
  #pragma unroll
  for (int i = 0; i < 3; ++i) {
    int idx = t + 256 * i;
    nI[i] = idx / 3; sI[i] = idx % 3;
    offI[i] = nI[i] * 2304 + sI[i] * 8;
  }

  f32x4 accG = {}, accQ = {}, accK = {};
  const u16* qbase = qkv + (long)b * 4096 * 2304 + h * 24;
  const u16* kbase = qbase + 768;
  int c0 = s * 4;

  uint4 rq[3], rk[3];
  PFQK(c0, rq, rk);
  __syncthreads();  // zero-init visible

  #pragma unroll
  for (int c = 0; c < 4; ++c) {
    WRQK(rq, rk);
    __syncthreads();
    if (c + 1 < 4) PFQK(c0 + c + 1, rq, rk);
    GRAM8;
    __syncthreads();
  }

  float* gb = gram + (long)(bh * 4 + s) * 3072;
  int row = fm * 16 + l4 * 4, col = fn * 16 + l16;
  #pragma unroll
  for (int j = 0; j < 4; ++j) {
    gb[(row + j) * 32 + col] = accG[j];
    gb[1024 + (row + j) * 32 + col] = accQ[j];
    gb[2048 + (row + j) * 32 + col] = accK[j];
  }
}

// ---------------- KB: reduce partials + softmax -> attnb ----------------
__global__ __launch_bounds__(32) void softmax_kernel(const float* __restrict__ gram,
                                                     const float* __restrict__ temperature,
                                                     u16* __restrict__ attnb) {
  int bh = blockIdx.x;
  int h = bh & 31;
  int d = threadIdx.x;
  u16* ab = attnb + bh * 1024;
  if (d < 24) {
    const float* gb = gram + (long)bh * 12288;
    float nq2 = 0.f, row[24], nk2[24];
    #pragma unroll
    for (int e = 0; e < 24; ++e) { row[e] = 0.f; nk2[e] = 0.f; }
    #pragma unroll
    for (int s = 0; s < 4; ++s) {
      const float* gs = gb + s * 3072;
      nq2 += gs[1024 + d * 33];
      #pragma unroll
      for (int e = 0; e < 24; ++e) {
        row[e] += gs[d * 32 + e];
        nk2[e] += gs[2048 + e * 33];
      }
    }
    float nq = fmaxf(sqrtf(fmaxf(nq2, 0.f)), 1e-12f);
    float tmp = temperature[h];
    float mx = -1e30f;
    #pragma unroll
    for (int e = 0; e < 24; ++e) {
      float nk = fmaxf(sqrtf(fmaxf(nk2[e], 0.f)), 1e-12f);
      row[e] = row[e] / (nq * nk) * tmp;
      mx = fmaxf(mx, row[e]);
    }
    float ssum = 0.f;
    #pragma unroll
    for (int e = 0; e < 24; ++e) { row[e] = __expf(row[e] - mx); ssum += row[e]; }
    float inv = 1.f / ssum;
    #pragma unroll
    for (int e = 0; e < 24; ++e) ab[d * 32 + e] = f2bf(row[e] * inv);
    #pragma unroll
    for (int e = 24; e < 32; ++e) ab[d * 32 + e] = 0;
  } else {
    #pragma unroll
    for (int e = 0; e < 32; ++e) ab[d * 32 + e] = 0;
  }
}

// ---------------- KC: y = attn @ v ----------------
__global__ __launch_bounds__(256) void pv_kernel(const u16* __restrict__ qkv,
                                                 const u16* __restrict__ attnb,
                                                 u16* __restrict__ yout) {
  __shared__ u16 vl[256][40];
  int bid = blockIdx.x;
  int bh = bid >> 4, c = bid & 15;
  int b = bh >> 5, h = bh & 31;
  int t = threadIdx.x;
  int w = t >> 6, l = t & 63;
  int l16 = l & 15, l4 = l >> 4;

  for (int i = t; i < 5120; i += 256) ((u32*)vl)[i] = 0;

  const u16* ab = attnb + bh * 1024;
  bf16x8 af0 = *(const bf16x8*)(ab + l16 * 32 + l4 * 8);
  bf16x8 af1 = *(const bf16x8*)(ab + (16 + l16) * 32 + l4 * 8);

  const u16* vbase = qkv + (long)b * 4096 * 2304 + h * 24 + 1536;
  uint4 rv[3];
  int nI[3], sI[3];
  #pragma unroll
  for (int i = 0; i < 3; ++i) {
    int idx = t + 256 * i;
    nI[i] = idx / 3; sI[i] = idx % 3;
    rv[i] = *(const uint4*)(vbase + (long)c * 589824 + nI[i] * 2304 + sI[i] * 8);
  }
  __syncthreads();
  #pragma unroll
  for (int i = 0; i < 3; ++i) *(uint4*)&vl[nI[i]][sI[i] * 8] = rv[i];
  __syncthreads();

  u16* ybase = yout + (long)(h * 8 + b) * 24 * 4096;
  int n0 = c * 256;
  f32x4 z = {};
  #pragma unroll
  for (int fnn = 0; fnn < 4; ++fnn) {
    int ncol = w * 64 + fnn * 16 + l16;
    bf16x8 bv = *(const bf16x8*)&vl[ncol][l4 * 8];
    f32x4 y0 = __builtin_amdgcn_mfma_f32_16x16x32_bf16(af0, bv, z, 0, 0, 0);
    f32x4 y1 = __builtin_amdgcn_mfma_f32_16x16x32_bf16(af1, bv, z, 0, 0, 0);
    int gn = n0 + ncol;
    #pragma unroll
    for (int j = 0; j < 4; ++j) {
      int d0 = l4 * 4 + j;
      ybase[(long)d0 * 4096 + gn] = f2bf(y0[j]);
      int d1 = 16 + d0;
      if (d1 < 24) ybase[(long)d1 * 4096 + gn] = f2bf(y1[j]);
    }
  }
}

extern "C" void kernel_launch(void* const* d_in, const int* in_sizes, int n_in,
                              void* d_out, int out_size, void* d_ws, size_t ws_size,
                              hipStream_t stream) {
  const float* x     = (const float*)d_in[0];
  const float* Wqkv  = (const float*)d_in[1];
  const float* bqkv  = (const float*)d_in[2];
  const float* temp  = (const float*)d_in[3];
  const float* Wproj = (const float*)d_in[4];
  const float* bproj = (const float*)d_in[5];
  float* out = (float*)d_out;

  // ws lifetimes: xb [cvt,K1], gram [KA,KB], y [KC,K3] share offset 0
  // (pairwise disjoint in time). attnb [KB,KC] overlays wqt (dead after K1).
  char* ws = (char*)d_ws;
  u16*   xb    = (u16*)(ws);            // 32768x768 bf16 (50.3 MB)
  float* gram  = (float*)(ws);          // 1024 x 3 x 1024 fp32 (12.6 MB)
  u16*   y     = (u16*)(ws);            // 32768x768 bf16 (H,B,D,N order)
  u16*   wqt   = (u16*)(ws + 50331648); // 2304x768 bf16
  u16*   attnb = (u16*)(ws + 50331648); // 256 x [32][32] bf16 (0.5 MB)
  u16*   wpt   = (u16*)(ws + 53870592); // 768x768 bf16
  u16*   qkv   = (u16*)(ws + 55050240); // 32768x2304 bf16

  cvt_kernel<<<12288, 256, 0, stream>>>(x, xb, 3145728);
  transpose_cvt2<<<dim3(96, 24), dim3(32, 8), 0, stream>>>(Wqkv, wqt, Wproj, wpt);
  gemm3c_kernel<24, 1><<<4608, 256, 0, stream>>>(xb, wqt, bqkv, qkv, 32768, 2304);
  gram_kernel<<<1024, 256, 0, stream>>>(qkv, gram);
  softmax_kernel<<<256, 32, 0, stream>>>(gram, temp, attnb);
  pv_kernel<<<4096, 256, 0, stream>>>(qkv, attnb, y);
  gemm3c_kernel<24, 0><<<1536, 256, 0, stream>>>(y, wpt, bproj, out, 32768, 768);
}

// Round 14
// 295.685 us; speedup vs baseline: 1.0714x; 1.0714x over previous
//
#include <hip/hip_runtime.h>
#include <hip/hip_bf16.h>

// XCAttention: B=8, N=4096, C=768, H=32, D=24
// Consolidated best-of-per-stage:
// K0a: x fp32->bf16 (BW floor ~24us); K0b: both W transposed (1 launch);
// K1: qkv GEMM 128x256, BK=32, 512 thr, 3-slot, 2 blocks/CU  [r7 best: 135us];
// KA: partial Grams; KB: softmax; KC: attn@v -> y  [r9 split: ~50us total];
// K3: proj GEMM 128x128, 256 thr, 3 blocks/CU, grid=2 full rounds [r12: ~43us].

#define DEVI __device__ __forceinline__

typedef __attribute__((ext_vector_type(8))) short bf16x8;
typedef __attribute__((ext_vector_type(4))) float f32x4;
typedef unsigned int u32;
typedef unsigned short u16;

DEVI u16 f2bf(float f) {  // RNE float->bf16
  union { float f; u32 u; } x; x.f = f;
  u32 r = x.u + 0x7FFFu + ((x.u >> 16) & 1u);
  return (u16)(r >> 16);
}

DEVI void gload_lds16(const void* g, void* l) {
  __builtin_amdgcn_global_load_lds((__attribute__((address_space(1))) void*)g,
                                   (__attribute__((address_space(3))) void*)l, 16, 0, 0);
}

// ---------------- K0a: fp32 -> bf16 convert ----------------
__global__ __launch_bounds__(256) void cvt_kernel(const float* __restrict__ in,
                                                  u16* __restrict__ out, int n8) {
  int i = blockIdx.x * 256 + threadIdx.x;
  if (i >= n8) return;
  long o = (long)i * 8;
  float4 a = *(const float4*)(in + o);
  float4 b = *(const float4*)(in + o + 4);
  uint4 v;
  v.x = f2bf(a.x) | ((u32)f2bf(a.y) << 16);
  v.y = f2bf(a.z) | ((u32)f2bf(a.w) << 16);
  v.z = f2bf(b.x) | ((u32)f2bf(b.y) << 16);
  v.w = f2bf(b.z) | ((u32)f2bf(b.w) << 16);
  *(uint4*)(out + o) = v;
}

// ---------------- K0b: both weights, W (K x N fp32) -> Wt (N x K bf16) ----------------
__global__ __launch_bounds__(256) void transpose_cvt2(const float* __restrict__ Wq,
                                                      u16* __restrict__ Wqt,
                                                      const float* __restrict__ Wp,
                                                      u16* __restrict__ Wpt) {
  __shared__ float tile[32][33];
  int bx = blockIdx.x;
  const float* W; u16* Wt; int N, n0;
  if (bx < 72) { W = Wq; Wt = Wqt; N = 2304; n0 = bx * 32; }
  else         { W = Wp; Wt = Wpt; N = 768;  n0 = (bx - 72) * 32; }
  int k0 = blockIdx.y * 32;
  int tx = threadIdx.x, ty = threadIdx.y;  // (32,8)
  #pragma unroll
  for (int i = 0; i < 4; ++i)
    tile[ty + 8 * i][tx] = W[(long)(k0 + ty + 8 * i) * N + n0 + tx];
  __syncthreads();
  #pragma unroll
  for (int i = 0; i < 4; ++i)
    Wt[(long)(n0 + ty + 8 * i) * 768 + k0 + tx] = f2bf(tile[tx][ty + 8 * i]);
}

// ---------------- K1: 128x256 bf16 GEMM, BK=32, 3-slot, 2 blocks/CU (r7) ----------------
#define STAGE_T(ktile, slot)                                                   \
  { gload_lds16(Ag + soffA + (ktile) * 32, lds + (slot) * 8192 + sdst);        \
    _Pragma("unroll") for (int j_ = 0; j_ < 2; ++j_)                           \
      gload_lds16(Bg + soffB[j_] + (ktile) * 32,                               \
                  lds + 24576 + (slot) * 16384 + j_ * 8192 + sdst); }

template<int NT>
__global__ __launch_bounds__(512, 4) void gemm2b_kernel(
    const u16* __restrict__ A, const u16* __restrict__ Bt,
    const float* __restrict__ bias, u16* __restrict__ Cout,
    int M, int N) {
  constexpr int K = NT * 32;
  __shared__ __attribute__((aligned(128))) char lds[73728];

  int nbx = N >> 8;
  int nwg = gridDim.x;
  int bid = blockIdx.x;
  bid = (bid & 7) * (nwg >> 3) + (bid >> 3);  // bijective XCD swizzle (nwg%8==0)
  int bx = bid % nbx, by = bid / nbx;

  int t = threadIdx.x;
  int w = t >> 6, l = t & 63;
  int wr = w >> 2, wc = w & 3;
  int l16 = l & 15, l4 = l >> 4;

  int cbb = (l4 * 16) ^ ((l16 & 8) << 2);
  int pA0 = (wr * 64 + l16) * 64 + cbb;          // + slot*8192  + mi*1024
  int pB0 = (wc * 64 + l16) * 64 + cbb;          // + 24576 + slot*16384 + n*1024

  int pa = t * 16;
  int la = pa ^ (((pa >> 9) & 1) << 5);
  int soffA = (la >> 6) * K + ((la & 63) >> 1);
  int soffB[2];
  #pragma unroll
  for (int j = 0; j < 2; ++j) {
    int p = (j * 512 + t) * 16;
    int lb = p ^ (((p >> 9) & 1) << 5);
    soffB[j] = (lb >> 6) * K + ((lb & 63) >> 1);
  }

  const u16* Ag = A + (long)by * 128 * K;
  const u16* Bg = Bt + (long)bx * 256 * K;
  int sdst = w * 1024;

  f32x4 acc[4][4] = {};

  STAGE_T(0, 0);
  STAGE_T(1, 1);

  #pragma unroll
  for (int kt = 0; kt < NT; ++kt) {
    int rs = kt % 3;
    if (kt + 2 < NT) {
      STAGE_T(kt + 2, (kt + 2) % 3);
      asm volatile("s_waitcnt vmcnt(6)" ::: "memory");
    } else if (kt + 2 == NT) {
      asm volatile("s_waitcnt vmcnt(3)" ::: "memory");
    } else {
      asm volatile("s_waitcnt vmcnt(0)" ::: "memory");
    }
    __builtin_amdgcn_sched_barrier(0);
    __builtin_amdgcn_s_barrier();
    __builtin_amdgcn_sched_barrier(0);

    bf16x8 aF[4], bF[4];
    #pragma unroll
    for (int mi = 0; mi < 4; ++mi)
      aF[mi] = *(const bf16x8*)(lds + rs * 8192 + mi * 1024 + pA0);
    #pragma unroll
    for (int n = 0; n < 4; ++n)
      bF[n] = *(const bf16x8*)(lds + 24576 + rs * 16384 + n * 1024 + pB0);

    __builtin_amdgcn_s_setprio(1);
    #pragma unroll
    for (int mi = 0; mi < 4; ++mi)
      #pragma unroll
      for (int n = 0; n < 4; ++n)
        acc[mi][n] = __builtin_amdgcn_mfma_f32_16x16x32_bf16(aF[mi], bF[n], acc[mi][n], 0, 0, 0);
    __builtin_amdgcn_s_setprio(0);
    __builtin_amdgcn_s_barrier();
    __builtin_amdgcn_sched_barrier(0);
  }

  #pragma unroll
  for (int mi = 0; mi < 4; ++mi) {
    int row0 = by * 128 + wr * 64 + mi * 16 + l4 * 4;
    #pragma unroll
    for (int n = 0; n < 4; ++n) {
      int col = bx * 256 + wc * 64 + n * 16 + l16;
      float bv = bias[col];
      #pragma unroll
      for (int j = 0; j < 4; ++j) {
        long idx = (long)(row0 + j) * N + col;
        Cout[idx] = f2bf(acc[mi][n][j] + bv);
      }
    }
  }
}

// ---------------- K3: 128x128 bf16 GEMM, 256 thr, 3 blocks/CU (r10/r12) ----------------
#define STAGE3(ktile, slot)                                                    \
  { _Pragma("unroll") for (int j_ = 0; j_ < 2; ++j_) {                         \
      gload_lds16(Ag + soffA[j_] + (ktile) * 32,                               \
                  lds + (slot) * 8192 + j_ * 4096 + sdst);                     \
      gload_lds16(Bg + soffB[j_] + (ktile) * 32,                               \
                  lds + 24576 + (slot) * 8192 + j_ * 4096 + sdst); } }

template<int NT>
__global__ __launch_bounds__(256, 3) void gemm3c_kernel(
    const u16* __restrict__ A, const u16* __restrict__ Bt,
    const float* __restrict__ bias, float* __restrict__ Cout,
    int M, int N) {
  constexpr int K = NT * 32;
  __shared__ __attribute__((aligned(128))) char lds[49152];

  int nbx = N >> 7;
  int nwg = gridDim.x;
  int bid = blockIdx.x;
  bid = (bid & 7) * (nwg >> 3) + (bid >> 3);
  int bx = bid % nbx, by = bid / nbx;

  int t = threadIdx.x;
  int w = t >> 6, l = t & 63;
  int wr = w >> 1, wc = w & 1;
  int l16 = l & 15, l4 = l >> 4;

  int cbb = (l4 * 16) ^ ((l16 & 8) << 2);
  int pA0 = (wr * 64 + l16) * 64 + cbb;
  int pB0 = (wc * 64 + l16) * 64 + cbb;

  int soffA[2], soffB[2];
  #pragma unroll
  for (int j = 0; j < 2; ++j) {
    int p = (j * 256 + t) * 16;
    int lb = p ^ (((p >> 9) & 1) << 5);
    soffA[j] = (lb >> 6) * K + ((lb & 63) >> 1);
    soffB[j] = soffA[j];
  }

  const u16* Ag = A + (long)by * 128 * K;
  const u16* Bg = Bt + (long)bx * 128 * K;
  int sdst = w * 1024;

  f32x4 acc[4][4] = {};

  STAGE3(0, 0);
  STAGE3(1, 1);

  #pragma unroll
  for (int kt = 0; kt < NT; ++kt) {
    int rs = kt % 3;
    if (kt + 2 < NT) {
      STAGE3(kt + 2, (kt + 2) % 3);
      asm volatile("s_waitcnt vmcnt(8)" ::: "memory");
    } else if (kt + 2 == NT) {
      asm volatile("s_waitcnt vmcnt(4)" ::: "memory");
    } else {
      asm volatile("s_waitcnt vmcnt(0)" ::: "memory");
    }
    __builtin_amdgcn_sched_barrier(0);
    __builtin_amdgcn_s_barrier();
    __builtin_amdgcn_sched_barrier(0);

    bf16x8 aF[4], bF[4];
    #pragma unroll
    for (int mi = 0; mi < 4; ++mi)
      aF[mi] = *(const bf16x8*)(lds + rs * 8192 + mi * 1024 + pA0);
    #pragma unroll
    for (int n = 0; n < 4; ++n)
      bF[n] = *(const bf16x8*)(lds + 24576 + rs * 8192 + n * 1024 + pB0);

    __builtin_amdgcn_s_setprio(1);
    #pragma unroll
    for (int mi = 0; mi < 4; ++mi)
      #pragma unroll
      for (int n = 0; n < 4; ++n)
        acc[mi][n] = __builtin_amdgcn_mfma_f32_16x16x32_bf16(aF[mi], bF[n], acc[mi][n], 0, 0, 0);
    __builtin_amdgcn_s_setprio(0);
    __builtin_amdgcn_s_barrier();
    __builtin_amdgcn_sched_barrier(0);
  }

  #pragma unroll
  for (int mi = 0; mi < 4; ++mi) {
    int row0 = by * 128 + wr * 64 + mi * 16 + l4 * 4;
    #pragma unroll
    for (int n = 0; n < 4; ++n) {
      int col = bx * 128 + wc * 64 + n * 16 + l16;
      float bv = bias[col];
      #pragma unroll
      for (int j = 0; j < 4; ++j) {
        long idx = (long)(row0 + j) * N + col;
        __builtin_nontemporal_store(acc[mi][n][j] + bv, Cout + idx);
      }
    }
  }
}

// ---------------- KA: partial Grams ----------------
#define PFQK(nc, rq, rk)                                                       \
  { long cb = (long)(nc) * 589824;                                             \
    _Pragma("unroll") for (int i = 0; i < 3; ++i) {                            \
      rq[i] = *(const uint4*)(qbase + cb + offI[i]);                           \
      rk[i] = *(const uint4*)(kbase + cb + offI[i]); } }

#define WRQK(rq, rk)                                                           \
  { _Pragma("unroll") for (int i = 0; i < 3; ++i) {                            \
      const u32* pq = (const u32*)&rq[i];                                      \
      const u32* pk = (const u32*)&rk[i];                                      \
      _Pragma("unroll") for (int j = 0; j < 4; ++j) {                          \
        int d = sI[i] * 8 + 2 * j;                                             \
        qt[d][nI[i]] = (u16)pq[j]; qt[d + 1][nI[i]] = (u16)(pq[j] >> 16);      \
        kt[d][nI[i]] = (u16)pk[j]; kt[d + 1][nI[i]] = (u16)(pk[j] >> 16); } } }

#define GRAM8                                                                  \
  { _Pragma("unroll") for (int ks = 0; ks < 8; ++ks) {                         \
      int koff = ks * 32 + l4 * 8;                                             \
      bf16x8 qa = *(const bf16x8*)&qt[fm * 16 + l16][koff];                    \
      bf16x8 qb = *(const bf16x8*)&qt[fn * 16 + l16][koff];                    \
      bf16x8 ka = *(const bf16x8*)&kt[fm * 16 + l16][koff];                    \
      bf16x8 kb = *(const bf16x8*)&kt[fn * 16 + l16][koff];                    \
      accG = __builtin_amdgcn_mfma_f32_16x16x32_bf16(qa, kb, accG, 0, 0, 0);   \
      accQ = __builtin_amdgcn_mfma_f32_16x16x32_bf16(qa, qb, accQ, 0, 0, 0);   \
      accK = __builtin_amdgcn_mfma_f32_16x16x32_bf16(ka, kb, accK, 0, 0, 0); } }

__global__ __launch_bounds__(256) void gram_kernel(const u16* __restrict__ qkv,
                                                   float* __restrict__ gram) {
  __shared__ u16 qt[32][280];
  __shared__ u16 kt[32][280];

  int bid = blockIdx.x;
  int bh = bid >> 2, s = bid & 3;
  int b = bh >> 5, h = bh & 31;
  int t = threadIdx.x;
  int w = t >> 6, l = t & 63;
  int l16 = l & 15, l4 = l >> 4;
  int fm = w >> 1, fn = w & 1;

  for (int i = t; i < 32 * 280; i += 256) { qt[0][i] = 0; kt[0][i] = 0; }

  int nI[3], sI[3], offI[3];
  #pragma unroll
  for (int i = 0; i < 3; ++i) {
    int idx = t + 256 * i;
    nI[i] = idx / 3; sI[i] = idx % 3;
    offI[i] = nI[i] * 2304 + sI[i] * 8;
  }

  f32x4 accG = {}, accQ = {}, accK = {};
  const u16* qbase = qkv + (long)b * 4096 * 2304 + h * 24;
  const u16* kbase = qbase + 768;
  int c0 = s * 4;

  uint4 rq[3], rk[3];
  PFQK(c0, rq, rk);
  __syncthreads();  // zero-init visible

  #pragma unroll
  for (int c = 0; c < 4; ++c) {
    WRQK(rq, rk);
    __syncthreads();
    if (c + 1 < 4) PFQK(c0 + c + 1, rq, rk);
    GRAM8;
    __syncthreads();
  }

  float* gb = gram + (long)(bh * 4 + s) * 3072;
  int row = fm * 16 + l4 * 4, col = fn * 16 + l16;
  #pragma unroll
  for (int j = 0; j < 4; ++j) {
    gb[(row + j) * 32 + col] = accG[j];
    gb[1024 + (row + j) * 32 + col] = accQ[j];
    gb[2048 + (row + j) * 32 + col] = accK[j];
  }
}

// ---------------- KB: reduce partials + softmax -> attnb ----------------
__global__ __launch_bounds__(32) void softmax_kernel(const float* __restrict__ gram,
                                                     const float* __restrict__ temperature,
                                                     u16* __restrict__ attnb) {
  int bh = blockIdx.x;
  int h = bh & 31;
  int d = threadIdx.x;
  u16* ab = attnb + bh * 1024;
  if (d < 24) {
    const float* gb = gram + (long)bh * 12288;
    float nq2 = 0.f, row[24], nk2[24];
    #pragma unroll
    for (int e = 0; e < 24; ++e) { row[e] = 0.f; nk2[e] = 0.f; }
    #pragma unroll
    for (int s = 0; s < 4; ++s) {
      const float* gs = gb + s * 3072;
      nq2 += gs[1024 + d * 33];
      #pragma unroll
      for (int e = 0; e < 24; ++e) {
        row[e] += gs[d * 32 + e];
        nk2[e] += gs[2048 + e * 33];
      }
    }
    float nq = fmaxf(sqrtf(fmaxf(nq2, 0.f)), 1e-12f);
    float tmp = temperature[h];
    float mx = -1e30f;
    #pragma unroll
    for (int e = 0; e < 24; ++e) {
      float nk = fmaxf(sqrtf(fmaxf(nk2[e], 0.f)), 1e-12f);
      row[e] = row[e] / (nq * nk) * tmp;
      mx = fmaxf(mx, row[e]);
    }
    float ssum = 0.f;
    #pragma unroll
    for (int e = 0; e < 24; ++e) { row[e] = __expf(row[e] - mx); ssum += row[e]; }
    float inv = 1.f / ssum;
    #pragma unroll
    for (int e = 0; e < 24; ++e) ab[d * 32 + e] = f2bf(row[e] * inv);
    #pragma unroll
    for (int e = 24; e < 32; ++e) ab[d * 32 + e] = 0;
  } else {
    #pragma unroll
    for (int e = 0; e < 32; ++e) ab[d * 32 + e] = 0;
  }
}

// ---------------- KC: y = attn @ v ----------------
__global__ __launch_bounds__(256) void pv_kernel(const u16* __restrict__ qkv,
                                                 const u16* __restrict__ attnb,
                                                 u16* __restrict__ yout) {
  __shared__ u16 vl[256][40];
  int bid = blockIdx.x;
  int bh = bid >> 4, c = bid & 15;
  int b = bh >> 5, h = bh & 31;
  int t = threadIdx.x;
  int w = t >> 6, l = t & 63;
  int l16 = l & 15, l4 = l >> 4;

  for (int i = t; i < 5120; i += 256) ((u32*)vl)[i] = 0;

  const u16* ab = attnb + bh * 1024;
  bf16x8 af0 = *(const bf16x8*)(ab + l16 * 32 + l4 * 8);
  bf16x8 af1 = *(const bf16x8*)(ab + (16 + l16) * 32 + l4 * 8);

  const u16* vbase = qkv + (long)b * 4096 * 2304 + h * 24 + 1536;
  uint4 rv[3];
  int nI[3], sI[3];
  #pragma unroll
  for (int i = 0; i < 3; ++i) {
    int idx = t + 256 * i;
    nI[i] = idx / 3; sI[i] = idx % 3;
    rv[i] = *(const uint4*)(vbase + (long)c * 589824 + nI[i] * 2304 + sI[i] * 8);
  }
  __syncthreads();
  #pragma unroll
  for (int i = 0; i < 3; ++i) *(uint4*)&vl[nI[i]][sI[i] * 8] = rv[i];
  __syncthreads();

  u16* ybase = yout + (long)(h * 8 + b) * 24 * 4096;
  int n0 = c * 256;
  f32x4 z = {};
  #pragma unroll
  for (int fnn = 0; fnn < 4; ++fnn) {
    int ncol = w * 64 + fnn * 16 + l16;
    bf16x8 bv = *(const bf16x8*)&vl[ncol][l4 * 8];
    f32x4 y0 = __builtin_amdgcn_mfma_f32_16x16x32_bf16(af0, bv, z, 0, 0, 0);
    f32x4 y1 = __builtin_amdgcn_mfma_f32_16x16x32_bf16(af1, bv, z, 0, 0, 0);
    int gn = n0 + ncol;
    #pragma unroll
    for (int j = 0; j < 4; ++j) {
      int d0 = l4 * 4 + j;
      ybase[(long)d0 * 4096 + gn] = f2bf(y0[j]);
      int d1 = 16 + d0;
      if (d1 < 24) ybase[(long)d1 * 4096 + gn] = f2bf(y1[j]);
    }
  }
}

extern "C" void kernel_launch(void* const* d_in, const int* in_sizes, int n_in,
                              void* d_out, int out_size, void* d_ws, size_t ws_size,
                              hipStream_t stream) {
  const float* x     = (const float*)d_in[0];
  const float* Wqkv  = (const float*)d_in[1];
  const float* bqkv  = (const float*)d_in[2];
  const float* temp  = (const float*)d_in[3];
  const float* Wproj = (const float*)d_in[4];
  const float* bproj = (const float*)d_in[5];
  float* out = (float*)d_out;

  // ws lifetimes: xb [cvt,K1], gram [KA,KB], y [KC,K3] share offset 0
  // (pairwise disjoint in time). attnb [KB,KC] overlays wqt (dead after K1).
  char* ws = (char*)d_ws;
  u16*   xb    = (u16*)(ws);            // 32768x768 bf16 (50.3 MB)
  float* gram  = (float*)(ws);          // 1024 x 3 x 1024 fp32 (12.6 MB)
  u16*   y     = (u16*)(ws);            // 32768x768 bf16 (H,B,D,N order)
  u16*   wqt   = (u16*)(ws + 50331648); // 2304x768 bf16
  u16*   attnb = (u16*)(ws + 50331648); // 256 x [32][32] bf16 (0.5 MB)
  u16*   wpt   = (u16*)(ws + 53870592); // 768x768 bf16
  u16*   qkv   = (u16*)(ws + 55050240); // 32768x2304 bf16

  cvt_kernel<<<12288, 256, 0, stream>>>(x, xb, 3145728);
  transpose_cvt2<<<dim3(96, 24), dim3(32, 8), 0, stream>>>(Wqkv, wqt, Wproj, wpt);
  gemm2b_kernel<24><<<2304, 512, 0, stream>>>(xb, wqt, bqkv, qkv, 32768, 2304);
  gram_kernel<<<1024, 256, 0, stream>>>(qkv, gram);
  softmax_kernel<<<256, 32, 0, stream>>>(gram, temp, attnb);
  pv_kernel<<<4096, 256, 0, stream>>>(qkv, attnb, y);
  gemm3c_kernel<24><<<1536, 256, 0, stream>>>(y, wpt, bproj, out, 32768, 768);
}

// Round 15
// 293.713 us; speedup vs baseline: 1.0786x; 1.0067x over previous
//
#include <hip/hip_runtime.h>
#include <hip/hip_bf16.h>

// XCAttention: B=8, N=4096, C=768, H=32, D=24
// prep: x fp32->bf16 + both W transposed (single launch);
// K1: qkv GEMM 128x256, BK=32, 512 thr, 3-slot, 2 blocks/CU  [best of 9: 135us];
// KA: partial Grams; KB: softmax; KC: attn@v 2 chunks/block;
// K3: proj GEMM 128x128, 256 thr, 3 blocks/CU, grid = 2 full rounds.

#define DEVI __device__ __forceinline__

typedef __attribute__((ext_vector_type(8))) short bf16x8;
typedef __attribute__((ext_vector_type(4))) float f32x4;
typedef unsigned int u32;
typedef unsigned short u16;

DEVI u16 f2bf(float f) {  // RNE float->bf16
  union { float f; u32 u; } x; x.f = f;
  u32 r = x.u + 0x7FFFu + ((x.u >> 16) & 1u);
  return (u16)(r >> 16);
}

DEVI void gload_lds16(const void* g, void* l) {
  __builtin_amdgcn_global_load_lds((__attribute__((address_space(1))) void*)g,
                                   (__attribute__((address_space(3))) void*)l, 16, 0, 0);
}

// ---------------- prep: cvt (blocks 0..12287) + weight transpose (12288..14591) ----------------
__global__ __launch_bounds__(256) void prep_kernel(const float* __restrict__ x,
                                                   u16* __restrict__ xb,
                                                   const float* __restrict__ Wq,
                                                   u16* __restrict__ Wqt,
                                                   const float* __restrict__ Wp,
                                                   u16* __restrict__ Wpt) {
  int bid = blockIdx.x;
  int t = threadIdx.x;
  if (bid < 12288) {
    long o = ((long)bid * 256 + t) * 8;
    float4 a = *(const float4*)(x + o);
    float4 b = *(const float4*)(x + o + 4);
    uint4 v;
    v.x = f2bf(a.x) | ((u32)f2bf(a.y) << 16);
    v.y = f2bf(a.z) | ((u32)f2bf(a.w) << 16);
    v.z = f2bf(b.x) | ((u32)f2bf(b.y) << 16);
    v.w = f2bf(b.z) | ((u32)f2bf(b.w) << 16);
    *(uint4*)(xb + o) = v;
    return;
  }
  __shared__ float tile[32][33];
  int tb = bid - 12288;          // 0..2303 = 96 x 24
  int bx = tb % 96, ky = tb / 96;
  const float* W; u16* Wt; int N, n0;
  if (bx < 72) { W = Wq; Wt = Wqt; N = 2304; n0 = bx * 32; }
  else         { W = Wp; Wt = Wpt; N = 768;  n0 = (bx - 72) * 32; }
  int k0 = ky * 32;
  int tx = t & 31, ty = t >> 5;  // (32,8)
  #pragma unroll
  for (int i = 0; i < 4; ++i)
    tile[ty + 8 * i][tx] = W[(long)(k0 + ty + 8 * i) * N + n0 + tx];
  __syncthreads();
  #pragma unroll
  for (int i = 0; i < 4; ++i)
    Wt[(long)(n0 + ty + 8 * i) * 768 + k0 + tx] = f2bf(tile[tx][ty + 8 * i]);
}

// ---------------- K1: 128x256 bf16 GEMM, BK=32, 3-slot, 2 blocks/CU (r7/r14) ----------------
#define STAGE_T(ktile, slot)                                                   \
  { gload_lds16(Ag + soffA + (ktile) * 32, lds + (slot) * 8192 + sdst);        \
    _Pragma("unroll") for (int j_ = 0; j_ < 2; ++j_)                           \
      gload_lds16(Bg + soffB[j_] + (ktile) * 32,                               \
                  lds + 24576 + (slot) * 16384 + j_ * 8192 + sdst); }

template<int NT>
__global__ __launch_bounds__(512, 4) void gemm2b_kernel(
    const u16* __restrict__ A, const u16* __restrict__ Bt,
    const float* __restrict__ bias, u16* __restrict__ Cout,
    int M, int N) {
  constexpr int K = NT * 32;
  __shared__ __attribute__((aligned(128))) char lds[73728];

  int nbx = N >> 8;
  int nwg = gridDim.x;
  int bid = blockIdx.x;
  bid = (bid & 7) * (nwg >> 3) + (bid >> 3);  // bijective XCD swizzle (nwg%8==0)
  int bx = bid % nbx, by = bid / nbx;

  int t = threadIdx.x;
  int w = t >> 6, l = t & 63;
  int wr = w >> 2, wc = w & 3;
  int l16 = l & 15, l4 = l >> 4;

  int cbb = (l4 * 16) ^ ((l16 & 8) << 2);
  int pA0 = (wr * 64 + l16) * 64 + cbb;          // + slot*8192  + mi*1024
  int pB0 = (wc * 64 + l16) * 64 + cbb;          // + 24576 + slot*16384 + n*1024

  int pa = t * 16;
  int la = pa ^ (((pa >> 9) & 1) << 5);
  int soffA = (la >> 6) * K + ((la & 63) >> 1);
  int soffB[2];
  #pragma unroll
  for (int j = 0; j < 2; ++j) {
    int p = (j * 512 + t) * 16;
    int lb = p ^ (((p >> 9) & 1) << 5);
    soffB[j] = (lb >> 6) * K + ((lb & 63) >> 1);
  }

  const u16* Ag = A + (long)by * 128 * K;
  const u16* Bg = Bt + (long)bx * 256 * K;
  int sdst = w * 1024;

  f32x4 acc[4][4] = {};

  STAGE_T(0, 0);
  STAGE_T(1, 1);

  #pragma unroll
  for (int kt = 0; kt < NT; ++kt) {
    int rs = kt % 3;
    if (kt + 2 < NT) {
      STAGE_T(kt + 2, (kt + 2) % 3);
      asm volatile("s_waitcnt vmcnt(6)" ::: "memory");
    } else if (kt + 2 == NT) {
      asm volatile("s_waitcnt vmcnt(3)" ::: "memory");
    } else {
      asm volatile("s_waitcnt vmcnt(0)" ::: "memory");
    }
    __builtin_amdgcn_sched_barrier(0);
    __builtin_amdgcn_s_barrier();
    __builtin_amdgcn_sched_barrier(0);

    bf16x8 aF[4], bF[4];
    #pragma unroll
    for (int mi = 0; mi < 4; ++mi)
      aF[mi] = *(const bf16x8*)(lds + rs * 8192 + mi * 1024 + pA0);
    #pragma unroll
    for (int n = 0; n < 4; ++n)
      bF[n] = *(const bf16x8*)(lds + 24576 + rs * 16384 + n * 1024 + pB0);

    __builtin_amdgcn_s_setprio(1);
    #pragma unroll
    for (int mi = 0; mi < 4; ++mi)
      #pragma unroll
      for (int n = 0; n < 4; ++n)
        acc[mi][n] = __builtin_amdgcn_mfma_f32_16x16x32_bf16(aF[mi], bF[n], acc[mi][n], 0, 0, 0);
    __builtin_amdgcn_s_setprio(0);
    __builtin_amdgcn_s_barrier();
    __builtin_amdgcn_sched_barrier(0);
  }

  #pragma unroll
  for (int mi = 0; mi < 4; ++mi) {
    int row0 = by * 128 + wr * 64 + mi * 16 + l4 * 4;
    #pragma unroll
    for (int n = 0; n < 4; ++n) {
      int col = bx * 256 + wc * 64 + n * 16 + l16;
      float bv = bias[col];
      #pragma unroll
      for (int j = 0; j < 4; ++j) {
        long idx = (long)(row0 + j) * N + col;
        Cout[idx] = f2bf(acc[mi][n][j] + bv);
      }
    }
  }
}

// ---------------- K3: 128x128 bf16 GEMM, 256 thr, 3 blocks/CU (r10/r12/r14) ----------------
#define STAGE3(ktile, slot)                                                    \
  { _Pragma("unroll") for (int j_ = 0; j_ < 2; ++j_) {                         \
      gload_lds16(Ag + soffA[j_] + (ktile) * 32,                               \
                  lds + (slot) * 8192 + j_ * 4096 + sdst);                     \
      gload_lds16(Bg + soffB[j_] + (ktile) * 32,                               \
                  lds + 24576 + (slot) * 8192 + j_ * 4096 + sdst); } }

template<int NT>
__global__ __launch_bounds__(256, 3) void gemm3c_kernel(
    const u16* __restrict__ A, const u16* __restrict__ Bt,
    const float* __restrict__ bias, float* __restrict__ Cout,
    int M, int N) {
  constexpr int K = NT * 32;
  __shared__ __attribute__((aligned(128))) char lds[49152];

  int nbx = N >> 7;
  int nwg = gridDim.x;
  int bid = blockIdx.x;
  bid = (bid & 7) * (nwg >> 3) + (bid >> 3);
  int bx = bid % nbx, by = bid / nbx;

  int t = threadIdx.x;
  int w = t >> 6, l = t & 63;
  int wr = w >> 1, wc = w & 1;
  int l16 = l & 15, l4 = l >> 4;

  int cbb = (l4 * 16) ^ ((l16 & 8) << 2);
  int pA0 = (wr * 64 + l16) * 64 + cbb;
  int pB0 = (wc * 64 + l16) * 64 + cbb;

  int soffA[2], soffB[2];
  #pragma unroll
  for (int j = 0; j < 2; ++j) {
    int p = (j * 256 + t) * 16;
    int lb = p ^ (((p >> 9) & 1) << 5);
    soffA[j] = (lb >> 6) * K + ((lb & 63) >> 1);
    soffB[j] = soffA[j];
  }

  const u16* Ag = A + (long)by * 128 * K;
  const u16* Bg = Bt + (long)bx * 128 * K;
  int sdst = w * 1024;

  f32x4 acc[4][4] = {};

  STAGE3(0, 0);
  STAGE3(1, 1);

  #pragma unroll
  for (int kt = 0; kt < NT; ++kt) {
    int rs = kt % 3;
    if (kt + 2 < NT) {
      STAGE3(kt + 2, (kt + 2) % 3);
      asm volatile("s_waitcnt vmcnt(8)" ::: "memory");
    } else if (kt + 2 == NT) {
      asm volatile("s_waitcnt vmcnt(4)" ::: "memory");
    } else {
      asm volatile("s_waitcnt vmcnt(0)" ::: "memory");
    }
    __builtin_amdgcn_sched_barrier(0);
    __builtin_amdgcn_s_barrier();
    __builtin_amdgcn_sched_barrier(0);

    bf16x8 aF[4], bF[4];
    #pragma unroll
    for (int mi = 0; mi < 4; ++mi)
      aF[mi] = *(const bf16x8*)(lds + rs * 8192 + mi * 1024 + pA0);
    #pragma unroll
    for (int n = 0; n < 4; ++n)
      bF[n] = *(const bf16x8*)(lds + 24576 + rs * 8192 + n * 1024 + pB0);

    __builtin_amdgcn_s_setprio(1);
    #pragma unroll
    for (int mi = 0; mi < 4; ++mi)
      #pragma unroll
      for (int n = 0; n < 4; ++n)
        acc[mi][n] = __builtin_amdgcn_mfma_f32_16x16x32_bf16(aF[mi], bF[n], acc[mi][n], 0, 0, 0);
    __builtin_amdgcn_s_setprio(0);
    __builtin_amdgcn_s_barrier();
    __builtin_amdgcn_sched_barrier(0);
  }

  #pragma unroll
  for (int mi = 0; mi < 4; ++mi) {
    int row0 = by * 128 + wr * 64 + mi * 16 + l4 * 4;
    #pragma unroll
    for (int n = 0; n < 4; ++n) {
      int col = bx * 128 + wc * 64 + n * 16 + l16;
      float bv = bias[col];
      #pragma unroll
      for (int j = 0; j < 4; ++j) {
        long idx = (long)(row0 + j) * N + col;
        __builtin_nontemporal_store(acc[mi][n][j] + bv, Cout + idx);
      }
    }
  }
}

// ---------------- KA: partial Grams ----------------
#define PFQK(nc, rq, rk)                                                       \
  { long cb = (long)(nc) * 589824;                                             \
    _Pragma("unroll") for (int i = 0; i < 3; ++i) {                            \
      rq[i] = *(const uint4*)(qbase + cb + offI[i]);                           \
      rk[i] = *(const uint4*)(kbase + cb + offI[i]); } }

#define WRQK(rq, rk)                                                           \
  { _Pragma("unroll") for (int i = 0; i < 3; ++i) {                            \
      const u32* pq = (const u32*)&rq[i];                                      \
      const u32* pk = (const u32*)&rk[i];                                      \
      _Pragma("unroll") for (int j = 0; j < 4; ++j) {                          \
        int d = sI[i] * 8 + 2 * j;                                             \
        qt[d][nI[i]] = (u16)pq[j]; qt[d + 1][nI[i]] = (u16)(pq[j] >> 16);      \
        kt[d][nI[i]] = (u16)pk[j]; kt[d + 1][nI[i]] = (u16)(pk[j] >> 16); } } }

#define GRAM8                                                                  \
  { _Pragma("unroll") for (int ks = 0; ks < 8; ++ks) {                         \
      int koff = ks * 32 + l4 * 8;                                             \
      bf16x8 qa = *(const bf16x8*)&qt[fm * 16 + l16][koff];                    \
      bf16x8 qb = *(const bf16x8*)&qt[fn * 16 + l16][koff];                    \
      bf16x8 ka = *(const bf16x8*)&kt[fm * 16 + l16][koff];                    \
      bf16x8 kb = *(const bf16x8*)&kt[fn * 16 + l16][koff];                    \
      accG = __builtin_amdgcn_mfma_f32_16x16x32_bf16(qa, kb, accG, 0, 0, 0);   \
      accQ = __builtin_amdgcn_mfma_f32_16x16x32_bf16(qa, qb, accQ, 0, 0, 0);   \
      accK = __builtin_amdgcn_mfma_f32_16x16x32_bf16(ka, kb, accK, 0, 0, 0); } }

__global__ __launch_bounds__(256) void gram_kernel(const u16* __restrict__ qkv,
                                                   float* __restrict__ gram) {
  __shared__ u16 qt[32][280];
  __shared__ u16 kt[32][280];

  int bid = blockIdx.x;
  int bh = bid >> 2, s = bid & 3;
  int b = bh >> 5, h = bh & 31;
  int t = threadIdx.x;
  int w = t >> 6, l = t & 63;
  int l16 = l & 15, l4 = l >> 4;
  int fm = w >> 1, fn = w & 1;

  for (int i = t; i < 32 * 280; i += 256) { qt[0][i] = 0; kt[0][i] = 0; }

  int nI[3], sI[3], offI[3];
  #pragma unroll
  for (int i = 0; i < 3; ++i) {
    int idx = t + 256 * i;
    nI[i] = idx / 3; sI[i] = idx % 3;
    offI[i] = nI[i] * 2304 + sI[i] * 8;
  }

  f32x4 accG = {}, accQ = {}, accK = {};
  const u16* qbase = qkv + (long)b * 4096 * 2304 + h * 24;
  const u16* kbase = qbase + 768;
  int c0 = s * 4;

  uint4 rq[3], rk[3];
  PFQK(c0, rq, rk);
  __syncthreads();  // zero-init visible

  #pragma unroll
  for (int c = 0; c < 4; ++c) {
    WRQK(rq, rk);
    __syncthreads();
    if (c + 1 < 4) PFQK(c0 + c + 1, rq, rk);
    GRAM8;
    __syncthreads();
  }

  float* gb = gram + (long)(bh * 4 + s) * 3072;
  int row = fm * 16 + l4 * 4, col = fn * 16 + l16;
  #pragma unroll
  for (int j = 0; j < 4; ++j) {
    gb[(row + j) * 32 + col] = accG[j];
    gb[1024 + (row + j) * 32 + col] = accQ[j];
    gb[2048 + (row + j) * 32 + col] = accK[j];
  }
}

// ---------------- KB: reduce partials + softmax -> attnb ----------------
__global__ __launch_bounds__(32) void softmax_kernel(const float* __restrict__ gram,
                                                     const float* __restrict__ temperature,
                                                     u16* __restrict__ attnb) {
  int bh = blockIdx.x;
  int h = bh & 31;
  int d = threadIdx.x;
  u16* ab = attnb + bh * 1024;
  if (d < 24) {
    const float* gb = gram + (long)bh * 12288;
    float nq2 = 0.f, row[24], nk2[24];
    #pragma unroll
    for (int e = 0; e < 24; ++e) { row[e] = 0.f; nk2[e] = 0.f; }
    #pragma unroll
    for (int s = 0; s < 4; ++s) {
      const float* gs = gb + s * 3072;
      nq2 += gs[1024 + d * 33];
      #pragma unroll
      for (int e = 0; e < 24; ++e) {
        row[e] += gs[d * 32 + e];
        nk2[e] += gs[2048 + e * 33];
      }
    }
    float nq = fmaxf(sqrtf(fmaxf(nq2, 0.f)), 1e-12f);
    float tmp = temperature[h];
    float mx = -1e30f;
    #pragma unroll
    for (int e = 0; e < 24; ++e) {
      float nk = fmaxf(sqrtf(fmaxf(nk2[e], 0.f)), 1e-12f);
      row[e] = row[e] / (nq * nk) * tmp;
      mx = fmaxf(mx, row[e]);
    }
    float ssum = 0.f;
    #pragma unroll
    for (int e = 0; e < 24; ++e) { row[e] = __expf(row[e] - mx); ssum += row[e]; }
    float inv = 1.f / ssum;
    #pragma unroll
    for (int e = 0; e < 24; ++e) ab[d * 32 + e] = f2bf(row[e] * inv);
    #pragma unroll
    for (int e = 24; e < 32; ++e) ab[d * 32 + e] = 0;
  } else {
    #pragma unroll
    for (int e = 0; e < 32; ++e) ab[d * 32 + e] = 0;
  }
}

// ---------------- KC: y = attn @ v, 2 chunks per block ----------------
#define PFV2(nc, rv)                                                           \
  { long cb = (long)(nc) * 589824;                                             \
    _Pragma("unroll") for (int i = 0; i < 3; ++i)                              \
      rv[i] = *(const uint4*)(vbase + cb + nI[i] * 2304 + sI[i] * 8); }

#define PV_STORE2(buf, nc)                                                     \
  { int n0 = (nc) * 256;                                                       \
    f32x4 z = {};                                                              \
    _Pragma("unroll") for (int fnn = 0; fnn < 4; ++fnn) {                      \
      int ncol = w * 64 + fnn * 16 + l16;                                      \
      bf16x8 bv = *(const bf16x8*)&vl[buf][ncol][l4 * 8];                      \
      f32x4 y0 = __builtin_amdgcn_mfma_f32_16x16x32_bf16(af0, bv, z, 0, 0, 0); \
      f32x4 y1 = __builtin_amdgcn_mfma_f32_16x16x32_bf16(af1, bv, z, 0, 0, 0); \
      int gn = n0 + ncol;                                                      \
      _Pragma("unroll") for (int j = 0; j < 4; ++j) {                          \
        int d0 = l4 * 4 + j;                                                   \
        ybase[(long)d0 * 4096 + gn] = f2bf(y0[j]);                             \
        int d1 = 16 + d0;                                                      \
        if (d1 < 24) ybase[(long)d1 * 4096 + gn] = f2bf(y1[j]); } } }

__global__ __launch_bounds__(256) void pv_kernel(const u16* __restrict__ qkv,
                                                 const u16* __restrict__ attnb,
                                                 u16* __restrict__ yout) {
  __shared__ u16 vl[2][256][40];
  int bid = blockIdx.x;              // 2048 = 256 bh x 8 chunk-pairs
  int bh = bid >> 3, cp = bid & 7;
  int b = bh >> 5, h = bh & 31;
  int t = threadIdx.x;
  int w = t >> 6, l = t & 63;
  int l16 = l & 15, l4 = l >> 4;

  for (int i = t; i < 10240; i += 256) ((u32*)vl)[i] = 0;

  const u16* ab = attnb + bh * 1024;
  bf16x8 af0 = *(const bf16x8*)(ab + l16 * 32 + l4 * 8);
  bf16x8 af1 = *(const bf16x8*)(ab + (16 + l16) * 32 + l4 * 8);

  const u16* vbase = qkv + (long)b * 4096 * 2304 + h * 24 + 1536;
  int nI[3], sI[3];
  #pragma unroll
  for (int i = 0; i < 3; ++i) {
    int idx = t + 256 * i;
    nI[i] = idx / 3; sI[i] = idx % 3;
  }
  int c0 = cp * 2;
  uint4 rvA[3], rvB[3];
  PFV2(c0, rvA);
  PFV2(c0 + 1, rvB);
  __syncthreads();  // zero-init visible
  #pragma unroll
  for (int i = 0; i < 3; ++i) {
    *(uint4*)&vl[0][nI[i]][sI[i] * 8] = rvA[i];
    *(uint4*)&vl[1][nI[i]][sI[i] * 8] = rvB[i];
  }
  __syncthreads();

  u16* ybase = yout + (long)(h * 8 + b) * 24 * 4096;
  PV_STORE2(0, c0);
  PV_STORE2(1, c0 + 1);
}

extern "C" void kernel_launch(void* const* d_in, const int* in_sizes, int n_in,
                              void* d_out, int out_size, void* d_ws, size_t ws_size,
                              hipStream_t stream) {
  const float* x     = (const float*)d_in[0];
  const float* Wqkv  = (const float*)d_in[1];
  const float* bqkv  = (const float*)d_in[2];
  const float* temp  = (const float*)d_in[3];
  const float* Wproj = (const float*)d_in[4];
  const float* bproj = (const float*)d_in[5];
  float* out = (float*)d_out;

  // ws lifetimes: xb [prep,K1], gram [KA,KB], y [KC,K3] share offset 0
  // (pairwise disjoint in time). attnb [KB,KC] overlays wqt (dead after K1).
  char* ws = (char*)d_ws;
  u16*   xb    = (u16*)(ws);            // 32768x768 bf16 (50.3 MB)
  float* gram  = (float*)(ws);          // 1024 x 3 x 1024 fp32 (12.6 MB)
  u16*   y     = (u16*)(ws);            // 32768x768 bf16 (H,B,D,N order)
  u16*   wqt   = (u16*)(ws + 50331648); // 2304x768 bf16
  u16*   attnb = (u16*)(ws + 50331648); // 256 x [32][32] bf16 (0.5 MB)
  u16*   wpt   = (u16*)(ws + 53870592); // 768x768 bf16
  u16*   qkv   = (u16*)(ws + 55050240); // 32768x2304 bf16

  prep_kernel<<<14592, 256, 0, stream>>>(x, xb, Wqkv, wqt, Wproj, wpt);
  gemm2b_kernel<24><<<2304, 512, 0, stream>>>(xb, wqt, bqkv, qkv, 32768, 2304);
  gram_kernel<<<1024, 256, 0, stream>>>(qkv, gram);
  softmax_kernel<<<256, 32, 0, stream>>>(gram, temp, attnb);
  pv_kernel<<<2048, 256, 0, stream>>>(qkv, attnb, y);
  gemm3c_kernel<24><<<1536, 256, 0, stream>>>(y, wpt, bproj, out, 32768, 768);
}